// Round 10
// baseline (291.584 us; speedup 1.0000x reference)
//
#include <hip/hip_runtime.h>
#include <stdint.h>

// RelScaleAttend: b=4, 16 heads, s=1024 (32x32 img), d=64. THREE kernels.
//
// Finding R0-R9: occupancy pins at ~3 blocks/CU for LDS=40960 => effective
// usable LDS is ~128KB/CU, so every prior round was under-occupied. This
// round shrinks attn LDS to 24576 B (ThS 8K + K dbuf 16K) -> 5-6 blocks/CU.
//
// K1 repack: K rows (swizzled bf16, as R9) + V in exact per-lane PV-fragment
//   order: VF[bh][kt64][chunk=ko*4+cn][lane]*16B, so attn loads V fragments
//   straight into MFMA operand registers (no LDS for V at all).
// K2 prep: R9's phase 0 verbatim (wave-uniform scalar table loads, fp32 dots
//   x LOG2E), then writes per-block attn-ready images into d_ws:
//     [0,8192)      ThS image (swizzled, byte-identical to R9's LDS content)
//     [8192,16384)  rwm2 per thread: 2 x f32x4 (tw - M, pre-gathered)
//     [16384,24576) qf per thread: 2 x bf16x8 (packed Q fragments)
// K3 attn: no phase 0, no Ql, no ds_writes. Prologue: 4 gl_lds (ThS + K0,
//   wave-local) + 4 reg loads (rwm,qf) + 8 V-frag loads. Loop: one
//   vmcnt(0)+barrier per 64-key tile; K from LDS dbuf, V from register dbuf.
//   Swapped-operand QK^T, per-lane STATIC-max softmax (exact), PV A-fragment
//   = lane's own p values. Numerics bit-identical to R9.

#define SCALE2 0.18033688f   // 0.125 * log2(e)
#define LOG2E  1.44269504f

typedef float  f32x4  __attribute__((ext_vector_type(4)));
typedef __bf16 bf16x8 __attribute__((ext_vector_type(8)));

#define AS1 __attribute__((address_space(1)))
#define AS3 __attribute__((address_space(3)))

__device__ inline bf16x8 pack8(f32x4 a, f32x4 b) {
    bf16x8 t;
    t[0]=(__bf16)a.x; t[1]=(__bf16)a.y; t[2]=(__bf16)a.z; t[3]=(__bf16)a.w;
    t[4]=(__bf16)b.x; t[5]=(__bf16)b.y; t[6]=(__bf16)b.z; t[7]=(__bf16)b.w;
    return t;
}

// ---------------- kernel 1: repack ----------------
__global__ __launch_bounds__(256) void repack(
        const float* __restrict__ kg, const float* __restrict__ vg,
        char* __restrict__ kp, char* __restrict__ vp) {
    __shared__ float Vt[64 * 68];
    const int t   = threadIdx.x;
    const int idx = blockIdx.x;            // 1024 = 64 bh x 16 kt
    const int bh  = idx >> 4, kt = idx & 15;
    const int bb  = bh >> 4, nh = bh & 15;
    const int inbase = bb * 1048576 + nh * 64;
    char* kout = kp + bh * 131072 + kt * 8192;
    char* vout = vp + bh * 131072 + kt * 8192;

    const int r  = t >> 2;                 // 0..63
    const int c0 = (t & 3) << 4;           // 0,16,32,48

    {   // K: row r, 16 dims -> swizzled bf16 (verbatim R9)
        const float* src = kg + inbase + (kt * 64 + r) * 1024 + c0;
        f32x4 a = ((const f32x4*)src)[0], b = ((const f32x4*)src)[1];
        f32x4 c = ((const f32x4*)src)[2], d = ((const f32x4*)src)[3];
        const int swz = (r & 7) << 4;
        *(bf16x8*)(kout + r * 128 + ((c0 * 2) ^ swz))      = pack8(a, b);
        *(bf16x8*)(kout + r * 128 + ((c0 * 2 + 16) ^ swz)) = pack8(c, d);
    }
    {   // V rows -> LDS
        const float* src = vg + inbase + (kt * 64 + r) * 1024 + c0;
        f32x4 a = ((const f32x4*)src)[0], b = ((const f32x4*)src)[1];
        f32x4 c = ((const f32x4*)src)[2], d = ((const f32x4*)src)[3];
        float* dst = &Vt[r * 68 + c0];
        ((f32x4*)dst)[0] = a; ((f32x4*)dst)[1] = b;
        ((f32x4*)dst)[2] = c; ((f32x4*)dst)[3] = d;
    }
    __syncthreads();
    {   // V -> per-lane PV fragments: chunk = ko*4+cn, lane l holds
        // V[key=(2ko+(j>>2))*16 + (l>>4)*4 + (j&3)][dim=cn*16+(l&15)], j=0..7
        const int wv = t >> 6, l = t & 63;
        const int n16v = l & 15, quadv = l >> 4;
#pragma unroll
        for (int i = 0; i < 2; ++i) {
            int chunk = wv * 2 + i, ko = chunk >> 2, cn = chunk & 3;
            int dim = cn * 16 + n16v;
            float x[8];
#pragma unroll
            for (int j = 0; j < 8; ++j)
                x[j] = Vt[((2 * ko + (j >> 2)) * 16 + quadv * 4 + (j & 3)) * 68 + dim];
            f32x4 a = {x[0], x[1], x[2], x[3]}, b = {x[4], x[5], x[6], x[7]};
            *(bf16x8*)(vout + chunk * 1024 + l * 16) = pack8(a, b);
        }
    }
}

// ---------------- kernel 2: prep (phase 0 extracted) ----------------
__global__ __launch_bounds__(256) void prep(
        const float* __restrict__ qg,
        const float* __restrict__ rph, const float* __restrict__ rpw,
        char* __restrict__ pz) {
    __shared__ float ThS[64 * 32];                // swizzled image
    __shared__ float Ql[64 * 68];
    __shared__ float TwS[64 * 36];

    const int tid  = threadIdx.x;
    const int w    = tid >> 6, lane = tid & 63;
    const int quad = lane >> 4, n16 = lane & 15;
    const int sw16 = (n16 & 7) << 4;

    // identical swizzle -> same logical block as attn's idx
    const int idx = blockIdx.x;
    const int xc  = idx & 7;
    const int r_  = idx >> 3;
    const int hp  = r_ & 15;
    const int bh  = xc + ((r_ >> 4) << 3);
    const int bb = bh >> 4, nh = bh & 15;
    const int h0 = hp << 1;
    const int base = bb * 1048576 + nh * 64;
    const int sq0  = h0 * 32;

    // stage Q rows (coalesced b128)
    {
        int r0 = tid >> 4, c0 = (tid & 15) << 2;
#pragma unroll
        for (int k = 0; k < 4; ++k) {
            int row = k * 16 + r0;
            f32x4 v = *(const f32x4*)(qg + base + (sq0 + row) * 1024 + c0);
            *(f32x4*)&Ql[row * 68 + c0] = v;
        }
    }
    __syncthreads();

    // rel dots with wave-uniform table addresses (verbatim R9)
    {
        const int wu = __builtin_amdgcn_readfirstlane(w);
        const float* qrow = &Ql[lane * 68];
        const float* hb = rph + h0 * 64;
        const float* wb = rpw - 33 * 64;
        float acc[24];
#pragma unroll
        for (int i = 0; i < 24; ++i) acc[i] = 0.f;
        for (int cq = 0; cq < 16; ++cq) {
            f32x4 qv = *(const f32x4*)(qrow + cq * 4);
#pragma unroll
            for (int i = 0; i < 24; ++i) {
                int cid = wu * 24 + i;
                const float* tb = (cid < 33 ? hb : wb) + cid * 64;
                f32x4 tv = *(const f32x4*)(tb + cq * 4);
                acc[i] += qv.x * tv.x + qv.y * tv.y + qv.z * tv.z + qv.w * tv.w;
            }
        }
#pragma unroll
        for (int i = 0; i < 24; ++i) {
            int cid = wu * 24 + i;
            float v = acc[i] * LOG2E;
            if (cid < 33) {
                int kh = (lane >> 5) + 31 - cid;
                if (kh >= 0 && kh < 32)
                    *(float*)((char*)ThS + lane * 128 + ((kh * 4) ^ ((lane & 7) << 4))) = v;
            } else {
                int kw = (lane & 31) + 31 - (cid - 33);
                if (kw >= 0 && kw < 32)
                    TwS[lane * 36 + kw] = v;
            }
        }
    }

    // Q fragments (verbatim R9)
    const int qn = w * 16 + n16;
    bf16x8 qf0, qf1;
    {
        const float* qp0 = &Ql[qn * 68 + quad * 8];
        const float* qp1 = &Ql[qn * 68 + 32 + quad * 8];
        qf0 = pack8(((const f32x4*)qp0)[0], ((const f32x4*)qp0)[1]);
        qf1 = pack8(((const f32x4*)qp1)[0], ((const f32x4*)qp1)[1]);
    }
    __syncthreads();   // ThS/TwS complete

    // rwm2 (verbatim R9)
    float rwm2[2][4];
    {
        float mh = -1e30f, mw = -1e30f;
#pragma unroll
        for (int i = 0; i < 8; ++i) {
            f32x4 a = *(const f32x4*)((const char*)ThS + qn * 128 + ((i * 16) ^ sw16));
            f32x4 b = *(const f32x4*)&TwS[qn * 36 + i * 4];
            mh = fmaxf(mh, fmaxf(fmaxf(a.x, a.y), fmaxf(a.z, a.w)));
            mw = fmaxf(mw, fmaxf(fmaxf(b.x, b.y), fmaxf(b.z, b.w)));
        }
        float M = mh + mw;
#pragma unroll
        for (int g = 0; g < 2; ++g)
#pragma unroll
            for (int r = 0; r < 4; ++r)
                rwm2[g][r] = TwS[qn * 36 + g * 16 + quad * 4 + r] - M;
    }

    // write attn-ready images
    char* wsb = pz + idx * 24576;
    *(f32x4*)(wsb + (size_t)tid * 32)      = ((const f32x4*)((const char*)ThS + tid * 32))[0];
    *(f32x4*)(wsb + (size_t)tid * 32 + 16) = ((const f32x4*)((const char*)ThS + tid * 32))[1];
    f32x4 rv0 = {rwm2[0][0], rwm2[0][1], rwm2[0][2], rwm2[0][3]};
    f32x4 rv1 = {rwm2[1][0], rwm2[1][1], rwm2[1][2], rwm2[1][3]};
    *(f32x4*)(wsb + 8192 + (size_t)tid * 32)      = rv0;
    *(f32x4*)(wsb + 8192 + (size_t)tid * 32 + 16) = rv1;
    *(bf16x8*)(wsb + 16384 + (size_t)tid * 32)      = qf0;
    *(bf16x8*)(wsb + 16384 + (size_t)tid * 32 + 16) = qf1;
}

// ---------------- kernel 3: attention ----------------
__global__ __launch_bounds__(256, 6) void attn(
        const char* __restrict__ kp, const char* __restrict__ vp,
        const char* __restrict__ pz, float* __restrict__ outg) {
    __shared__ __align__(16) char ThSb[8192];     // rel_h image (wave-local rows)
    __shared__ __align__(16) char arena[16384];   // K double buffer

    const int tid  = threadIdx.x;
    const int w    = tid >> 6, lane = tid & 63;
    const int quad = lane >> 4, n16 = lane & 15;
    const int sw16 = (n16 & 7) << 4;

    const int idx = blockIdx.x;
    const int xc  = idx & 7;
    const int r_  = idx >> 3;
    const int hp  = r_ & 15;
    const int bh  = xc + ((r_ >> 4) << 3);
    const int bb = bh >> 4, nh = bh & 15;
    const int base = bb * 1048576 + nh * 64;
    const int sq0  = (hp << 1) * 32;

    const char* kpb = kp + bh * 131072;
    const char* vpb = vp + bh * 131072;
    const char* wsb = pz + idx * 24576;

    // ---- prologue: ThS image + K tile 0 via gl_lds (wave-local slices) ----
    __builtin_amdgcn_global_load_lds((const AS1 void*)(wsb + w * 2048 + lane * 16),
                                     (AS3 void*)(ThSb + w * 2048), 16, 0, 0);
    __builtin_amdgcn_global_load_lds((const AS1 void*)(wsb + w * 2048 + 1024 + lane * 16),
                                     (AS3 void*)(ThSb + w * 2048 + 1024), 16, 0, 0);
    __builtin_amdgcn_global_load_lds((const AS1 void*)(kpb + w * 2048 + lane * 16),
                                     (AS3 void*)(arena + w * 2048), 16, 0, 0);
    __builtin_amdgcn_global_load_lds((const AS1 void*)(kpb + w * 2048 + 1024 + lane * 16),
                                     (AS3 void*)(arena + w * 2048 + 1024), 16, 0, 0);

    // per-thread images
    f32x4 rv0 = *(const f32x4*)(wsb + 8192 + tid * 32);
    f32x4 rv1 = *(const f32x4*)(wsb + 8192 + tid * 32 + 16);
    bf16x8 qf0 = *(const bf16x8*)(wsb + 16384 + tid * 32);
    bf16x8 qf1 = *(const bf16x8*)(wsb + 16384 + tid * 32 + 16);

    // V tile 0 fragments (register double buffer)
    bf16x8 vA[8], vB[8];
#pragma unroll
    for (int c = 0; c < 8; ++c)
        vA[c] = *(const bf16x8*)(vpb + c * 1024 + lane * 16);

    const int qn = w * 16 + n16;
    float lr = 0.f;
    f32x4 oc[4];
#pragma unroll
    for (int i = 0; i < 4; ++i) oc[i] = (f32x4){0.f, 0.f, 0.f, 0.f};

#define BODY(KT, VC, VN) do {                                                     \
    asm volatile("s_waitcnt vmcnt(0)" ::: "memory");                              \
    __builtin_amdgcn_s_barrier();                                                 \
    if ((KT) + 1 < 16) {                                                          \
        const char* kn_ = kpb + ((KT) + 1) * 8192;                                \
        char* kd_ = arena + ((((KT) + 1) & 1) * 8192);                            \
        __builtin_amdgcn_global_load_lds((const AS1 void*)(kn_ + w * 2048 + lane * 16),          \
                                         (AS3 void*)(kd_ + w * 2048), 16, 0, 0);                 \
        __builtin_amdgcn_global_load_lds((const AS1 void*)(kn_ + w * 2048 + 1024 + lane * 16),   \
                                         (AS3 void*)(kd_ + w * 2048 + 1024), 16, 0, 0);          \
        const char* vn_ = vpb + ((KT) + 1) * 8192 + lane * 16;                    \
        _Pragma("unroll")                                                         \
        for (int c_ = 0; c_ < 8; ++c_) VN[c_] = *(const bf16x8*)(vn_ + c_ * 1024);\
    }                                                                             \
    const char* kbase_ = arena + (((KT) & 1) * 8192);                             \
    f32x4 s_[4];                                                                  \
    _Pragma("unroll")                                                             \
    for (int g_ = 0; g_ < 4; ++g_) s_[g_] = (f32x4){0.f, 0.f, 0.f, 0.f};          \
    _Pragma("unroll")                                                             \
    for (int ch_ = 0; ch_ < 2; ++ch_)                                             \
        _Pragma("unroll")                                                         \
        for (int g_ = 0; g_ < 4; ++g_) {                                          \
            bf16x8 kf_ = *(const bf16x8*)(kbase_ + (g_ * 16 + n16) * 128          \
                                          + ((ch_ * 64 + quad * 16) ^ sw16));     \
            s_[g_] = __builtin_amdgcn_mfma_f32_16x16x32_bf16(kf_, ch_ ? qf1 : qf0,\
                                                             s_[g_], 0, 0, 0);    \
        }                                                                         \
    float2 rhp_ = *(const float2*)(ThSb + qn * 128 + (((KT) * 8) ^ sw16));        \
    float p_[4][4];                                                               \
    _Pragma("unroll")                                                             \
    for (int g_ = 0; g_ < 4; ++g_) {                                              \
        const float rb_ = (g_ >= 2) ? rhp_.y : rhp_.x;                            \
        const f32x4 rw_ = (g_ & 1) ? rv1 : rv0;                                   \
        _Pragma("unroll")                                                         \
        for (int r_2 = 0; r_2 < 4; ++r_2)                                         \
            p_[g_][r_2] = __builtin_amdgcn_exp2f(fmaf(s_[g_][r_2], SCALE2,        \
                                                      rb_ + rw_[r_2]));           \
    }                                                                             \
    _Pragma("unroll")                                                             \
    for (int g_ = 0; g_ < 4; ++g_)                                                \
        lr += ((p_[g_][0] + p_[g_][1]) + (p_[g_][2] + p_[g_][3]));                \
    bf16x8 pf_[2];                                                                \
    _Pragma("unroll")                                                             \
    for (int ko_ = 0; ko_ < 2; ++ko_) {                                           \
        bf16x8 t_;                                                                \
        t_[0] = (__bf16)p_[2 * ko_][0];     t_[1] = (__bf16)p_[2 * ko_][1];       \
        t_[2] = (__bf16)p_[2 * ko_][2];     t_[3] = (__bf16)p_[2 * ko_][3];       \
        t_[4] = (__bf16)p_[2 * ko_ + 1][0]; t_[5] = (__bf16)p_[2 * ko_ + 1][1];   \
        t_[6] = (__bf16)p_[2 * ko_ + 1][2]; t_[7] = (__bf16)p_[2 * ko_ + 1][3];   \
        pf_[ko_] = t_;                                                            \
    }                                                                             \
    _Pragma("unroll")                                                             \
    for (int ko_ = 0; ko_ < 2; ++ko_)                                             \
        _Pragma("unroll")                                                         \
        for (int cn_ = 0; cn_ < 4; ++cn_)                                         \
            oc[cn_] = __builtin_amdgcn_mfma_f32_16x16x32_bf16(pf_[ko_],           \
                          VC[ko_ * 4 + cn_], oc[cn_], 0, 0, 0);                   \
} while (0)

    for (int kt = 0; kt < 16; kt += 2) {
        BODY(kt, vA, vB);
        BODY(kt + 1, vB, vA);
    }
#undef BODY

    // ---- epilogue: full row-sum per query, redistribute, store ----
    lr += __shfl_xor(lr, 16);
    lr += __shfl_xor(lr, 32);
    float linv[4];
#pragma unroll
    for (int r = 0; r < 4; ++r)
        linv[r] = 1.f / __shfl(lr, quad * 4 + r, 64);

    // oc[cn][r] = O[query = w*16 + quad*4 + r][dim = cn*16 + n16]
#pragma unroll
    for (int r = 0; r < 4; ++r) {
        int ob = base + (sq0 + w * 16 + quad * 4 + r) * 1024 + n16;
        outg[ob]      = oc[0][r] * linv[r];
        outg[ob + 16] = oc[1][r] * linv[r];
        outg[ob + 32] = oc[2][r] * linv[r];
        outg[ob + 48] = oc[3][r] * linv[r];
    }
}

extern "C" void kernel_launch(void* const* d_in, const int* in_sizes, int n_in,
                              void* d_out, int out_size, void* d_ws, size_t ws_size,
                              hipStream_t stream) {
    (void)in_sizes; (void)n_in; (void)out_size; (void)ws_size;
    const float* q   = (const float*)d_in[0];
    const float* k   = (const float*)d_in[1];
    const float* v   = (const float*)d_in[2];
    const float* rph = (const float*)d_in[3];
    const float* rpw = (const float*)d_in[4];
    char* kp = (char*)d_ws;                       // 8 MB packed K
    char* vp = kp + 8388608;                      // 8 MB packed V fragments
    char* pz = vp + 8388608;                      // 24 MB prep images
    repack<<<dim3(1024), 256, 0, stream>>>(k, v, kp, vp);
    prep  <<<dim3(1024), 256, 0, stream>>>(q, rph, rpw, pz);
    attn  <<<dim3(1024), 256, 0, stream>>>(kp, vp, pz, (float*)d_out);
}